// Round 1
// baseline (4592.469 us; speedup 1.0000x reference)
//
#include <hip/hip_runtime.h>

#define NB 8
#define NN 10000
#define NE 160000
#define NNODES (NB*NN)          // 80000
#define NEDGE (NB*NE)           // 1280000
#define FIN 5
#define HID 128
#define EMB 256
#define ALAST 10
#define PROJ_IN (HID*5 + ALAST + 1)  // 651

__global__ void k_init_deg(float* deg) {
    int i = blockIdx.x*256 + threadIdx.x;
    if (i < NNODES) deg[i] = 1.0f;   // self-loop contribution
}

__global__ void k_count(const int* __restrict__ edges, float* __restrict__ deg,
                        int* __restrict__ srcI, int* __restrict__ dstI) {
    int e = blockIdx.x*256 + threadIdx.x;
    if (e >= NEDGE) return;
    int b = e / NE;
    int w = e - b*NE;
    int s = edges[(size_t)b*2*NE + w]      + b*NN;
    int d = edges[(size_t)b*2*NE + NE + w] + b*NN;
    srcI[e] = s;
    dstI[e] = d;
    unsafeAtomicAdd(&deg[d], 1.0f);
}

__global__ void k_rsqrt(float* deg) {
    int i = blockIdx.x*256 + threadIdx.x;
    if (i < NNODES) deg[i] = rsqrtf(deg[i]);   // deg>=1 always
}

// h = x @ W1^T ; hs = h * dinv[n]; acc initialized to hs (self-loop msg)
__global__ void k_h1(const float* __restrict__ x, const float* __restrict__ W1,
                     const float* __restrict__ dinv,
                     float* __restrict__ hs, float* __restrict__ acc) {
    __shared__ float w[HID*FIN];
    for (int i = threadIdx.x; i < HID*FIN; i += 256) w[i] = W1[i];
    __syncthreads();
    int idx = blockIdx.x*256 + threadIdx.x;
    if (idx >= NNODES*HID) return;
    int n = idx >> 7;
    int j = idx & 127;
    const float* xr = x + n*FIN;
    const float* wr = w + j*FIN;
    float h = xr[0]*wr[0] + xr[1]*wr[1] + xr[2]*wr[2] + xr[3]*wr[3] + xr[4]*wr[4];
    float v = h * dinv[n];
    hs[idx]  = v;
    acc[idx] = v;
}

// one edge per 32 lanes; float4 over the 128 features; atomic accumulate
__global__ void k_scatter(const int* __restrict__ srcI, const int* __restrict__ dstI,
                          const float* __restrict__ hs, float* __restrict__ acc) {
    int t = blockIdx.x*256 + threadIdx.x;
    int e = t >> 5;
    if (e >= NEDGE) return;
    int l = (t & 31) << 2;
    int s = srcI[e];
    int d = dstI[e];
    const float4 v = *(const float4*)(hs + (size_t)s*HID + l);
    float* a = acc + (size_t)d*HID + l;
    unsafeAtomicAdd(a+0, v.x);
    unsafeAtomicAdd(a+1, v.y);
    unsafeAtomicAdd(a+2, v.z);
    unsafeAtomicAdd(a+3, v.w);
}

__global__ void k_finalize(const float* __restrict__ acc, const float* __restrict__ dinv,
                           const float* __restrict__ bias, float* __restrict__ out) {
    int idx = blockIdx.x*256 + threadIdx.x;
    if (idx >= NNODES*HID) return;
    int n = idx >> 7, j = idx & 127;
    float v = acc[idx] * dinv[n] + bias[j];
    out[idx] = fmaxf(v, 0.0f);
}

// Layer-2 dense: C[64n x 128j] = X[64 x 128] @ W2^T, K split in two 64-chunks.
// wt staged transposed (stride 132 kills bank conflicts); per-thread 8n x 4j tile.
__global__ __launch_bounds__(256) void k_h2(
        const float* __restrict__ x, const float* __restrict__ W2,
        const float* __restrict__ dinv,
        float* __restrict__ hs, float* __restrict__ acc) {
    __shared__ float xs[64*64];
    __shared__ float wt[64*132];
    int tid = threadIdx.x;
    int n0g = blockIdx.x * 64;
    int jq = tid & 31;
    int j0 = jq * 4;
    int nb = (tid >> 5) * 8;
    float a[8][4];
    #pragma unroll
    for (int i = 0; i < 8; ++i) { a[i][0]=0.f; a[i][1]=0.f; a[i][2]=0.f; a[i][3]=0.f; }
    for (int kh = 0; kh < 128; kh += 64) {
        for (int i = tid; i < 128*64; i += 256) {
            int j = i >> 6, kk = i & 63;
            wt[kk*132 + j] = W2[j*128 + kh + kk];
        }
        for (int i = tid; i < 64*64; i += 256) {
            int nn = i >> 6, kk = i & 63;
            xs[i] = x[(size_t)(n0g + nn)*128 + kh + kk];
        }
        __syncthreads();
        for (int k = 0; k < 64; k += 4) {
            float4 w0 = *(const float4*)&wt[(k+0)*132 + j0];
            float4 w1 = *(const float4*)&wt[(k+1)*132 + j0];
            float4 w2 = *(const float4*)&wt[(k+2)*132 + j0];
            float4 w3 = *(const float4*)&wt[(k+3)*132 + j0];
            #pragma unroll
            for (int i = 0; i < 8; ++i) {
                float4 xq = *(const float4*)&xs[(nb+i)*64 + k];
                a[i][0] += xq.x*w0.x + xq.y*w1.x + xq.z*w2.x + xq.w*w3.x;
                a[i][1] += xq.x*w0.y + xq.y*w1.y + xq.z*w2.y + xq.w*w3.y;
                a[i][2] += xq.x*w0.z + xq.y*w1.z + xq.z*w2.z + xq.w*w3.z;
                a[i][3] += xq.x*w0.w + xq.y*w1.w + xq.z*w2.w + xq.w*w3.w;
            }
        }
        __syncthreads();
    }
    #pragma unroll
    for (int i = 0; i < 8; ++i) {
        int n = n0g + nb + i;
        float dv = dinv[n];
        float4 v = make_float4(a[i][0]*dv, a[i][1]*dv, a[i][2]*dv, a[i][3]*dv);
        *(float4*)&hs[(size_t)n*HID + j0]  = v;
        *(float4*)&acc[(size_t)n*HID + j0] = v;
    }
}

__global__ void k_gather(const float* __restrict__ x, const int* __restrict__ avail,
                         const int* __restrict__ pos, const float* __restrict__ actions,
                         const float* __restrict__ steps, float* __restrict__ cx) {
    int b = blockIdx.x;
    int t = threadIdx.x;
    __shared__ int p[5];
    if (t < 4) p[t] = avail[b*4 + t] + b*NN;
    if (t == 4) p[4] = pos[b] + b*NN;
    __syncthreads();
    for (int i = t; i < 5*HID; i += 256) {
        int pi = i >> 7, j = i & 127;
        cx[b*PROJ_IN + i] = x[(size_t)p[pi]*HID + j];
    }
    if (t < ALAST) cx[b*PROJ_IN + 5*HID + t] = actions[b*ALAST + t];
    if (t == ALAST) cx[b*PROJ_IN + 5*HID + ALAST] = steps[b];
}

__global__ void k_mlp1(const float* __restrict__ cx, const float* __restrict__ Wp1,
                       const float* __restrict__ bp1, float* __restrict__ hm) {
    int b = blockIdx.x;
    int j = threadIdx.x;
    __shared__ float c[PROJ_IN];
    for (int i = threadIdx.x; i < PROJ_IN; i += 256) c[i] = cx[b*PROJ_IN + i];
    __syncthreads();
    const float* wr = Wp1 + (size_t)j*PROJ_IN;
    float s = bp1[j];
    for (int k = 0; k < PROJ_IN; ++k) s += c[k]*wr[k];
    hm[b*EMB + j] = fmaxf(s, 0.f);
}

__global__ void k_mlp2(const float* __restrict__ hm, const float* __restrict__ Wp2,
                       const float* __restrict__ bp2, float* __restrict__ out) {
    int b = blockIdx.x;
    int j = threadIdx.x;
    __shared__ float c[EMB];
    if (threadIdx.x < EMB) c[threadIdx.x] = hm[b*EMB + threadIdx.x];
    __syncthreads();
    const float* wr = Wp2 + (size_t)j*EMB;
    float s = bp2[j];
    for (int k = 0; k < EMB; ++k) s += c[k]*wr[k];
    out[b*EMB + j] = s;
}

extern "C" void kernel_launch(void* const* d_in, const int* in_sizes, int n_in,
                              void* d_out, int out_size, void* d_ws, size_t ws_size,
                              hipStream_t stream) {
    const float* graph_x = (const float*)d_in[0];
    const int*   edges   = (const int*)d_in[1];
    const int*   pos     = (const int*)d_in[2];
    const int*   avail   = (const int*)d_in[3];
    const float* actions = (const float*)d_in[4];
    const float* steps   = (const float*)d_in[5];
    const float* W1  = (const float*)d_in[6];
    const float* b1  = (const float*)d_in[7];
    const float* W2  = (const float*)d_in[8];
    const float* b2  = (const float*)d_in[9];
    const float* Wp1 = (const float*)d_in[10];
    const float* bp1 = (const float*)d_in[11];
    const float* Wp2 = (const float*)d_in[12];
    const float* bp2 = (const float*)d_in[13];
    float* out = (float*)d_out;

    char* ws = (char*)d_ws;
    size_t off = 0;
    float* deg  = (float*)(ws + off); off += (size_t)NNODES*4;
    int*   srcI = (int*)  (ws + off); off += (size_t)NEDGE*4;
    int*   dstI = (int*)  (ws + off); off += (size_t)NEDGE*4;
    float* bufA = (float*)(ws + off); off += (size_t)NNODES*HID*4;  // hs1 / hs2
    float* bufB = (float*)(ws + off); off += (size_t)NNODES*HID*4;  // acc1 / acc2
    float* bufC = (float*)(ws + off); off += (size_t)NNODES*HID*4;  // x2 / x3
    float* cx   = (float*)(ws + off); off += (size_t)NB*PROJ_IN*4;
    float* hm   = (float*)(ws + off); off += (size_t)NB*EMB*4;

    k_init_deg<<<(NNODES+255)/256, 256, 0, stream>>>(deg);
    k_count<<<(NEDGE+255)/256, 256, 0, stream>>>(edges, deg, srcI, dstI);
    k_rsqrt<<<(NNODES+255)/256, 256, 0, stream>>>(deg);

    // layer 1
    k_h1<<<(NNODES*HID)/256, 256, 0, stream>>>(graph_x, W1, deg, bufA, bufB);
    k_scatter<<<((size_t)NEDGE*32)/256, 256, 0, stream>>>(srcI, dstI, bufA, bufB);
    k_finalize<<<(NNODES*HID)/256, 256, 0, stream>>>(bufB, deg, b1, bufC);

    // layer 2
    k_h2<<<NNODES/64, 256, 0, stream>>>(bufC, W2, deg, bufA, bufB);
    k_scatter<<<((size_t)NEDGE*32)/256, 256, 0, stream>>>(srcI, dstI, bufA, bufB);
    k_finalize<<<(NNODES*HID)/256, 256, 0, stream>>>(bufB, deg, b2, bufC);

    // head
    k_gather<<<NB, 256, 0, stream>>>(bufC, avail, pos, actions, steps, cx);
    k_mlp1<<<NB, 256, 0, stream>>>(cx, Wp1, bp1, hm);
    k_mlp2<<<NB, 256, 0, stream>>>(hm, Wp2, bp2, out);
}

// Round 2
// 531.293 us; speedup vs baseline: 8.6440x; 8.6440x over previous
//
#include <hip/hip_runtime.h>

#define NB 8
#define NN 10000
#define NE 160000
#define NNODES (NB*NN)          // 80000
#define NEDGE (NB*NE)           // 1280000
#define FIN 5
#define HID 128
#define EMB 256
#define ALAST 10
#define PROJ_IN (HID*5 + ALAST + 1)  // 651
#define NBLK ((NNODES+255)/256)      // 313

__global__ void k_zero(int* cnt) {
    int i = blockIdx.x*256 + threadIdx.x;
    if (i < NNODES) cnt[i] = 0;
}

__global__ void k_hist(const int* __restrict__ edges, int* __restrict__ cnt) {
    int e = blockIdx.x*256 + threadIdx.x;
    if (e >= NEDGE) return;
    int b = e / NE, w = e - b*NE;
    int d = edges[(size_t)b*2*NE + NE + w] + b*NN;
    atomicAdd(&cnt[d], 1);
}

// exclusive scan, stage 1: per-block scan of 256, emit block sums
__global__ void k_scan1(const int* __restrict__ cnt, int* __restrict__ rowStart,
                        int* __restrict__ bsum) {
    __shared__ int sh[256];
    int tid = threadIdx.x;
    int i = blockIdx.x*256 + tid;
    int v = (i < NNODES) ? cnt[i] : 0;
    sh[tid] = v;
    __syncthreads();
    for (int off = 1; off < 256; off <<= 1) {
        int t = (tid >= off) ? sh[tid - off] : 0;
        __syncthreads();
        sh[tid] += t;
        __syncthreads();
    }
    if (i < NNODES) rowStart[i] = sh[tid] - v;          // exclusive
    if (tid == 255) bsum[blockIdx.x] = sh[255];
}

// stage 2: exclusive scan of the 313 block sums, one block of 512
__global__ void k_scan2(int* bsum) {
    __shared__ int sh[512];
    int tid = threadIdx.x;
    int v = (tid < NBLK) ? bsum[tid] : 0;
    sh[tid] = v;
    __syncthreads();
    for (int off = 1; off < 512; off <<= 1) {
        int t = (tid >= off) ? sh[tid - off] : 0;
        __syncthreads();
        sh[tid] += t;
        __syncthreads();
    }
    if (tid < NBLK) bsum[tid] = sh[tid] - v;            // exclusive
}

// stage 3: add block offsets, init cursor, set rowStart[NNODES]
__global__ void k_scan3(int* __restrict__ rowStart, const int* __restrict__ bsum,
                        int* __restrict__ cursor) {
    int i = blockIdx.x*256 + threadIdx.x;
    if (i < NNODES) {
        int r = rowStart[i] + bsum[blockIdx.x];
        rowStart[i] = r;
        cursor[i]   = r;
    }
    if (i == 0) rowStart[NNODES] = NEDGE;
}

__global__ void k_fill(const int* __restrict__ edges, int* __restrict__ cursor,
                       int* __restrict__ csrSrc) {
    int e = blockIdx.x*256 + threadIdx.x;
    if (e >= NEDGE) return;
    int b = e / NE, w = e - b*NE;
    int s = edges[(size_t)b*2*NE + w]      + b*NN;
    int d = edges[(size_t)b*2*NE + NE + w] + b*NN;
    int p = atomicAdd(&cursor[d], 1);
    csrSrc[p] = s;
}

__global__ void k_dinv(const int* __restrict__ cnt, float* __restrict__ dinv) {
    int i = blockIdx.x*256 + threadIdx.x;
    if (i < NNODES) dinv[i] = rsqrtf(1.0f + (float)cnt[i]);  // +1 = self loop
}

// h = x @ W1^T, scaled by dinv → hs (self-loop handled in k_agg)
__global__ void k_h1(const float* __restrict__ x, const float* __restrict__ W1,
                     const float* __restrict__ dinv, float* __restrict__ hs) {
    __shared__ float w[HID*FIN];
    for (int i = threadIdx.x; i < HID*FIN; i += 256) w[i] = W1[i];
    __syncthreads();
    int idx = blockIdx.x*256 + threadIdx.x;
    if (idx >= NNODES*HID) return;
    int n = idx >> 7;
    int j = idx & 127;
    const float* xr = x + n*FIN;
    const float* wr = w + j*FIN;
    float h = xr[0]*wr[0] + xr[1]*wr[1] + xr[2]*wr[2] + xr[3]*wr[3] + xr[4]*wr[4];
    hs[idx] = h * dinv[n];
}

// gather-side aggregation, one wave per node, fused norm+bias+relu
__global__ __launch_bounds__(256) void k_agg(
        const int* __restrict__ rowStart, const int* __restrict__ csrSrc,
        const float* __restrict__ hs, const float* __restrict__ dinv,
        const float* __restrict__ bias, float* __restrict__ out) {
    int n = (blockIdx.x*256 + threadIdx.x) >> 6;
    if (n >= NNODES) return;
    int lane = threadIdx.x & 63;
    const float2* hp = (const float2*)hs;
    float2 acc = hp[(size_t)n*64 + lane];               // self-loop message
    int beg = rowStart[n], end = rowStart[n+1];
    for (int i = beg; i < end; i += 64) {
        int m = end - i; if (m > 64) m = 64;
        int s = (lane < m) ? csrSrc[i + lane] : 0;
        for (int j = 0; j < m; ++j) {
            int sj = __shfl(s, j);
            float2 v = hp[(size_t)sj*64 + lane];
            acc.x += v.x; acc.y += v.y;
        }
    }
    float dv = dinv[n];
    float2 bb = ((const float2*)bias)[lane];
    float2 o;
    o.x = fmaxf(acc.x*dv + bb.x, 0.0f);
    o.y = fmaxf(acc.y*dv + bb.y, 0.0f);
    ((float2*)out)[(size_t)n*64 + lane] = o;
}

// Layer-2 dense: hs[64n x 128j] = (X[64 x 128] @ W2^T) * dinv
__global__ __launch_bounds__(256) void k_h2(
        const float* __restrict__ x, const float* __restrict__ W2,
        const float* __restrict__ dinv, float* __restrict__ hs) {
    __shared__ float xs[64*64];
    __shared__ float wt[64*132];
    int tid = threadIdx.x;
    int n0g = blockIdx.x * 64;
    int jq = tid & 31;
    int j0 = jq * 4;
    int nb = (tid >> 5) * 8;
    float a[8][4];
    #pragma unroll
    for (int i = 0; i < 8; ++i) { a[i][0]=0.f; a[i][1]=0.f; a[i][2]=0.f; a[i][3]=0.f; }
    for (int kh = 0; kh < 128; kh += 64) {
        for (int i = tid; i < 128*64; i += 256) {
            int j = i >> 6, kk = i & 63;
            wt[kk*132 + j] = W2[j*128 + kh + kk];
        }
        for (int i = tid; i < 64*64; i += 256) {
            int nn = i >> 6, kk = i & 63;
            xs[i] = x[(size_t)(n0g + nn)*128 + kh + kk];
        }
        __syncthreads();
        for (int k = 0; k < 64; k += 4) {
            float4 w0 = *(const float4*)&wt[(k+0)*132 + j0];
            float4 w1 = *(const float4*)&wt[(k+1)*132 + j0];
            float4 w2 = *(const float4*)&wt[(k+2)*132 + j0];
            float4 w3 = *(const float4*)&wt[(k+3)*132 + j0];
            #pragma unroll
            for (int i = 0; i < 8; ++i) {
                float4 xq = *(const float4*)&xs[(nb+i)*64 + k];
                a[i][0] += xq.x*w0.x + xq.y*w1.x + xq.z*w2.x + xq.w*w3.x;
                a[i][1] += xq.x*w0.y + xq.y*w1.y + xq.z*w2.y + xq.w*w3.y;
                a[i][2] += xq.x*w0.z + xq.y*w1.z + xq.z*w2.z + xq.w*w3.z;
                a[i][3] += xq.x*w0.w + xq.y*w1.w + xq.z*w2.w + xq.w*w3.w;
            }
        }
        __syncthreads();
    }
    #pragma unroll
    for (int i = 0; i < 8; ++i) {
        int n = n0g + nb + i;
        float dv = dinv[n];
        float4 v = make_float4(a[i][0]*dv, a[i][1]*dv, a[i][2]*dv, a[i][3]*dv);
        *(float4*)&hs[(size_t)n*HID + j0] = v;
    }
}

__global__ void k_gather(const float* __restrict__ x, const int* __restrict__ avail,
                         const int* __restrict__ pos, const float* __restrict__ actions,
                         const float* __restrict__ steps, float* __restrict__ cx) {
    int b = blockIdx.x;
    int t = threadIdx.x;
    __shared__ int p[5];
    if (t < 4) p[t] = avail[b*4 + t] + b*NN;
    if (t == 4) p[4] = pos[b] + b*NN;
    __syncthreads();
    for (int i = t; i < 5*HID; i += 256) {
        int pi = i >> 7, j = i & 127;
        cx[b*PROJ_IN + i] = x[(size_t)p[pi]*HID + j];
    }
    if (t < ALAST) cx[b*PROJ_IN + 5*HID + t] = actions[b*ALAST + t];
    if (t == ALAST) cx[b*PROJ_IN + 5*HID + ALAST] = steps[b];
}

__global__ void k_mlp1(const float* __restrict__ cx, const float* __restrict__ Wp1,
                       const float* __restrict__ bp1, float* __restrict__ hm) {
    int b = blockIdx.x;
    int j = threadIdx.x;
    __shared__ float c[PROJ_IN];
    for (int i = threadIdx.x; i < PROJ_IN; i += 256) c[i] = cx[b*PROJ_IN + i];
    __syncthreads();
    const float* wr = Wp1 + (size_t)j*PROJ_IN;
    float s = bp1[j];
    for (int k = 0; k < PROJ_IN; ++k) s += c[k]*wr[k];
    hm[b*EMB + j] = fmaxf(s, 0.f);
}

__global__ void k_mlp2(const float* __restrict__ hm, const float* __restrict__ Wp2,
                       const float* __restrict__ bp2, float* __restrict__ out) {
    int b = blockIdx.x;
    int j = threadIdx.x;
    __shared__ float c[EMB];
    if (threadIdx.x < EMB) c[threadIdx.x] = hm[b*EMB + threadIdx.x];
    __syncthreads();
    const float* wr = Wp2 + (size_t)j*EMB;
    float s = bp2[j];
    for (int k = 0; k < EMB; ++k) s += c[k]*wr[k];
    out[b*EMB + j] = s;
}

extern "C" void kernel_launch(void* const* d_in, const int* in_sizes, int n_in,
                              void* d_out, int out_size, void* d_ws, size_t ws_size,
                              hipStream_t stream) {
    const float* graph_x = (const float*)d_in[0];
    const int*   edges   = (const int*)d_in[1];
    const int*   pos     = (const int*)d_in[2];
    const int*   avail   = (const int*)d_in[3];
    const float* actions = (const float*)d_in[4];
    const float* steps   = (const float*)d_in[5];
    const float* W1  = (const float*)d_in[6];
    const float* b1  = (const float*)d_in[7];
    const float* W2  = (const float*)d_in[8];
    const float* b2  = (const float*)d_in[9];
    const float* Wp1 = (const float*)d_in[10];
    const float* bp1 = (const float*)d_in[11];
    const float* Wp2 = (const float*)d_in[12];
    const float* bp2 = (const float*)d_in[13];
    float* out = (float*)d_out;

    char* ws = (char*)d_ws;
    size_t off = 0;
    int*   cnt      = (int*)  (ws + off); off += (size_t)NNODES*4;
    int*   rowStart = (int*)  (ws + off); off += (size_t)(NNODES+1)*4;
    int*   bsum     = (int*)  (ws + off); off += 512*4;
    int*   cursor   = (int*)  (ws + off); off += (size_t)NNODES*4;
    int*   csrSrc   = (int*)  (ws + off); off += (size_t)NEDGE*4;
    float* dinv     = (float*)(ws + off); off += (size_t)NNODES*4;
    float* bufA     = (float*)(ws + off); off += (size_t)NNODES*HID*4;  // hs
    float* bufC     = (float*)(ws + off); off += (size_t)NNODES*HID*4;  // layer out
    float* cx       = (float*)(ws + off); off += (size_t)NB*PROJ_IN*4;
    float* hm       = (float*)(ws + off); off += (size_t)NB*EMB*4;

    // CSR build (once, reused by both layers)
    k_zero<<<NBLK, 256, 0, stream>>>(cnt);
    k_hist<<<(NEDGE+255)/256, 256, 0, stream>>>(edges, cnt);
    k_scan1<<<NBLK, 256, 0, stream>>>(cnt, rowStart, bsum);
    k_scan2<<<1, 512, 0, stream>>>(bsum);
    k_scan3<<<NBLK, 256, 0, stream>>>(rowStart, bsum, cursor);
    k_fill<<<(NEDGE+255)/256, 256, 0, stream>>>(edges, cursor, csrSrc);
    k_dinv<<<NBLK, 256, 0, stream>>>(cnt, dinv);

    // layer 1
    k_h1<<<(NNODES*HID)/256, 256, 0, stream>>>(graph_x, W1, dinv, bufA);
    k_agg<<<(NNODES*64)/256, 256, 0, stream>>>(rowStart, csrSrc, bufA, dinv, b1, bufC);

    // layer 2
    k_h2<<<NNODES/64, 256, 0, stream>>>(bufC, W2, dinv, bufA);
    k_agg<<<(NNODES*64)/256, 256, 0, stream>>>(rowStart, csrSrc, bufA, dinv, b2, bufC);

    // head
    k_gather<<<NB, 256, 0, stream>>>(bufC, avail, pos, actions, steps, cx);
    k_mlp1<<<NB, 256, 0, stream>>>(cx, Wp1, bp1, hm);
    k_mlp2<<<NB, 256, 0, stream>>>(hm, Wp2, bp2, out);
}

// Round 3
// 438.541 us; speedup vs baseline: 10.4721x; 1.2115x over previous
//
#include <hip/hip_runtime.h>

#define NB 8
#define NN 10000
#define NE 160000
#define NNODES (NB*NN)          // 80000
#define NEDGE (NB*NE)           // 1280000
#define FIN 5
#define HID 128
#define EMB 256
#define ALAST 10
#define PROJ_IN (HID*5 + ALAST + 1)  // 651
#define NBLK ((NNODES+255)/256)      // 313

__global__ void k_hist(const int* __restrict__ edges, int* __restrict__ cnt) {
    int e = blockIdx.x*256 + threadIdx.x;
    if (e >= NEDGE) return;
    int b = e / NE, w = e - b*NE;
    int d = edges[(size_t)b*2*NE + NE + w] + b*NN;
    atomicAdd(&cnt[d], 1);
}

__global__ void k_scan1(const int* __restrict__ cnt, int* __restrict__ rowStart,
                        int* __restrict__ bsum) {
    __shared__ int sh[256];
    int tid = threadIdx.x;
    int i = blockIdx.x*256 + tid;
    int v = (i < NNODES) ? cnt[i] : 0;
    sh[tid] = v;
    __syncthreads();
    for (int off = 1; off < 256; off <<= 1) {
        int t = (tid >= off) ? sh[tid - off] : 0;
        __syncthreads();
        sh[tid] += t;
        __syncthreads();
    }
    if (i < NNODES) rowStart[i] = sh[tid] - v;          // exclusive
    if (tid == 255) bsum[blockIdx.x] = sh[255];
}

__global__ void k_scan2(int* bsum) {
    __shared__ int sh[512];
    int tid = threadIdx.x;
    int v = (tid < NBLK) ? bsum[tid] : 0;
    sh[tid] = v;
    __syncthreads();
    for (int off = 1; off < 512; off <<= 1) {
        int t = (tid >= off) ? sh[tid - off] : 0;
        __syncthreads();
        sh[tid] += t;
        __syncthreads();
    }
    if (tid < NBLK) bsum[tid] = sh[tid] - v;            // exclusive
}

// add block offsets, init cursor, rowStart[NNODES], dinv
__global__ void k_scan3(int* __restrict__ rowStart, const int* __restrict__ bsum,
                        int* __restrict__ cursor, const int* __restrict__ cnt,
                        float* __restrict__ dinv) {
    int i = blockIdx.x*256 + threadIdx.x;
    if (i < NNODES) {
        int r = rowStart[i] + bsum[blockIdx.x];
        rowStart[i] = r;
        cursor[i]   = r;
        dinv[i]     = rsqrtf(1.0f + (float)cnt[i]);     // +1 = self loop
    }
    if (i == 0) rowStart[NNODES] = NEDGE;
}

__global__ void k_fill(const int* __restrict__ edges, int* __restrict__ cursor,
                       int* __restrict__ csrSrc) {
    int e = blockIdx.x*256 + threadIdx.x;
    if (e >= NEDGE) return;
    int b = e / NE, w = e - b*NE;
    int s = edges[(size_t)b*2*NE + w]      + b*NN;
    int d = edges[(size_t)b*2*NE + NE + w] + b*NN;
    int p = atomicAdd(&cursor[d], 1);
    csrSrc[p] = s;
}

// h = x @ W1^T, scaled by dinv → hs
__global__ void k_h1(const float* __restrict__ x, const float* __restrict__ W1,
                     const float* __restrict__ dinv, float* __restrict__ hs) {
    __shared__ float w[HID*FIN];
    for (int i = threadIdx.x; i < HID*FIN; i += 256) w[i] = W1[i];
    __syncthreads();
    int idx = blockIdx.x*256 + threadIdx.x;
    if (idx >= NNODES*HID) return;
    int n = idx >> 7;
    int j = idx & 127;
    const float* xr = x + n*FIN;
    const float* wr = w + j*FIN;
    float h = xr[0]*wr[0] + xr[1]*wr[1] + xr[2]*wr[2] + xr[3]*wr[3] + xr[4]*wr[4];
    hs[idx] = h * dinv[n];
}

// gather aggregation: 32 lanes per node (float4), 8 nodes/block.
// XCD swizzle: blockIdx%8 -> graph, so each XCD's L2 sees ~one graph's hs slab.
__global__ __launch_bounds__(256) void k_agg(
        const int* __restrict__ rowStart, const int* __restrict__ csrSrc,
        const float* __restrict__ hs, const float* __restrict__ dinv,
        const float* __restrict__ bias, float* __restrict__ out) {
    int g = blockIdx.x;
    int graph = g & 7;
    int i = g >> 3;                         // 0..1249
    int n = graph*NN + i*8 + (threadIdx.x >> 5);
    int lane = threadIdx.x & 31;
    const float4* hp = (const float4*)hs;
    float4 acc = hp[(size_t)n*32 + lane];   // self-loop message
    int beg = rowStart[n], end = rowStart[n+1];
    for (int e = beg; e < end; e += 32) {
        int m = end - e; if (m > 32) m = 32;
        int s = (lane < m) ? csrSrc[e + lane] : 0;
        for (int j = 0; j < m; ++j) {
            int sj = __shfl(s, j, 32);
            float4 v = hp[(size_t)sj*32 + lane];
            acc.x += v.x; acc.y += v.y; acc.z += v.z; acc.w += v.w;
        }
    }
    float dv = dinv[n];
    float4 bb = ((const float4*)bias)[lane];
    float4 o;
    o.x = fmaxf(acc.x*dv + bb.x, 0.0f);
    o.y = fmaxf(acc.y*dv + bb.y, 0.0f);
    o.z = fmaxf(acc.z*dv + bb.z, 0.0f);
    o.w = fmaxf(acc.w*dv + bb.w, 0.0f);
    ((float4*)out)[(size_t)n*32 + lane] = o;
}

// Layer-2 dense: hs = (X @ W2^T) * dinv. 128x128 block tile, 8x8 per thread.
// LDS holds K-chunk transposed: xs[k][m], wt[k][j] -> all reads <=2-way banked.
#define KC 32
__global__ __launch_bounds__(256) void k_h2(
        const float* __restrict__ x, const float* __restrict__ W2,
        const float* __restrict__ dinv, float* __restrict__ hs) {
    __shared__ float xs[KC*128];
    __shared__ float wt[KC*128];
    int tid = threadIdx.x;
    int m0g = blockIdx.x * 128;
    int tx = tid & 15, ty = tid >> 4;
    int m0 = ty*8;
    int j0 = tx*4;
    int r  = tid >> 1;                  // staging row 0..127
    int kq = (tid & 1) * 16;            // staging k sub-chunk
    float a[8][8];
    #pragma unroll
    for (int i = 0; i < 8; ++i)
        #pragma unroll
        for (int j = 0; j < 8; ++j) a[i][j] = 0.f;

    for (int kh = 0; kh < 128; kh += KC) {
        float4 xv[4], wv[4];
        #pragma unroll
        for (int c = 0; c < 4; ++c) {
            xv[c] = *(const float4*)&x[(size_t)(m0g + r)*128 + kh + kq + 4*c];
            wv[c] = *(const float4*)&W2[(size_t)r*128 + kh + kq + 4*c];
        }
        __syncthreads();               // protect prev iter's reads
        #pragma unroll
        for (int c = 0; c < 4; ++c) {
            xs[(kq+4*c+0)*128 + r] = xv[c].x;
            xs[(kq+4*c+1)*128 + r] = xv[c].y;
            xs[(kq+4*c+2)*128 + r] = xv[c].z;
            xs[(kq+4*c+3)*128 + r] = xv[c].w;
            wt[(kq+4*c+0)*128 + r] = wv[c].x;
            wt[(kq+4*c+1)*128 + r] = wv[c].y;
            wt[(kq+4*c+2)*128 + r] = wv[c].z;
            wt[(kq+4*c+3)*128 + r] = wv[c].w;
        }
        __syncthreads();
        for (int k = 0; k < KC; ++k) {
            float4 xa = *(const float4*)&xs[k*128 + m0];
            float4 xb = *(const float4*)&xs[k*128 + m0 + 4];
            float4 wa = *(const float4*)&wt[k*128 + j0];
            float4 wb = *(const float4*)&wt[k*128 + j0 + 64];
            float xr[8] = {xa.x,xa.y,xa.z,xa.w,xb.x,xb.y,xb.z,xb.w};
            float wr[8] = {wa.x,wa.y,wa.z,wa.w,wb.x,wb.y,wb.z,wb.w};
            #pragma unroll
            for (int i = 0; i < 8; ++i)
                #pragma unroll
                for (int j = 0; j < 8; ++j)
                    a[i][j] += xr[i]*wr[j];
        }
    }
    #pragma unroll
    for (int i = 0; i < 8; ++i) {
        int n = m0g + m0 + i;
        float dv = dinv[n];
        float4 v0 = make_float4(a[i][0]*dv, a[i][1]*dv, a[i][2]*dv, a[i][3]*dv);
        float4 v1 = make_float4(a[i][4]*dv, a[i][5]*dv, a[i][6]*dv, a[i][7]*dv);
        *(float4*)&hs[(size_t)n*HID + j0]      = v0;
        *(float4*)&hs[(size_t)n*HID + 64 + j0] = v1;
    }
}

// fused gather + MLP1 + MLP2, one block per batch row
__global__ __launch_bounds__(256) void k_head(
        const float* __restrict__ x, const int* __restrict__ avail,
        const int* __restrict__ pos, const float* __restrict__ actions,
        const float* __restrict__ steps,
        const float* __restrict__ Wp1, const float* __restrict__ bp1,
        const float* __restrict__ Wp2, const float* __restrict__ bp2,
        float* __restrict__ out) {
    int b = blockIdx.x;
    int t = threadIdx.x;
    __shared__ float c[PROJ_IN];
    __shared__ float hm[EMB];
    __shared__ int p[5];
    if (t < 4) p[t] = avail[b*4 + t] + b*NN;
    if (t == 4) p[4] = pos[b] + b*NN;
    __syncthreads();
    for (int i = t; i < 5*HID; i += 256) {
        int pi = i >> 7, j = i & 127;
        c[i] = x[(size_t)p[pi]*HID + j];
    }
    if (t < ALAST) c[5*HID + t] = actions[b*ALAST + t];
    if (t == ALAST) c[5*HID + ALAST] = steps[b];
    __syncthreads();
    {
        const float* wr = Wp1 + (size_t)t*PROJ_IN;
        float s = bp1[t];
        for (int k = 0; k < PROJ_IN; ++k) s += c[k]*wr[k];
        hm[t] = fmaxf(s, 0.f);
    }
    __syncthreads();
    {
        const float* wr = Wp2 + (size_t)t*EMB;
        float s = bp2[t];
        for (int k = 0; k < EMB; ++k) s += hm[k]*wr[k];
        out[b*EMB + t] = s;
    }
}

extern "C" void kernel_launch(void* const* d_in, const int* in_sizes, int n_in,
                              void* d_out, int out_size, void* d_ws, size_t ws_size,
                              hipStream_t stream) {
    const float* graph_x = (const float*)d_in[0];
    const int*   edges   = (const int*)d_in[1];
    const int*   pos     = (const int*)d_in[2];
    const int*   avail   = (const int*)d_in[3];
    const float* actions = (const float*)d_in[4];
    const float* steps   = (const float*)d_in[5];
    const float* W1  = (const float*)d_in[6];
    const float* b1  = (const float*)d_in[7];
    const float* W2  = (const float*)d_in[8];
    const float* b2  = (const float*)d_in[9];
    const float* Wp1 = (const float*)d_in[10];
    const float* bp1 = (const float*)d_in[11];
    const float* Wp2 = (const float*)d_in[12];
    const float* bp2 = (const float*)d_in[13];
    float* out = (float*)d_out;

    char* ws = (char*)d_ws;
    size_t off = 0;
    #define ALLOC(ptrname, type, nelem) \
        type* ptrname = (type*)(ws + off); off = (off + (size_t)(nelem)*sizeof(type) + 255) & ~(size_t)255;
    ALLOC(cnt,      int,   NNODES)
    ALLOC(rowStart, int,   NNODES+1)
    ALLOC(bsum,     int,   512)
    ALLOC(cursor,   int,   NNODES)
    ALLOC(csrSrc,   int,   NEDGE)
    ALLOC(dinv,     float, NNODES)
    ALLOC(bufA,     float, (size_t)NNODES*HID)   // hs
    ALLOC(bufC,     float, (size_t)NNODES*HID)   // layer out
    #undef ALLOC

    hipMemsetAsync(cnt, 0, (size_t)NNODES*4, stream);
    k_hist<<<(NEDGE+255)/256, 256, 0, stream>>>(edges, cnt);
    k_scan1<<<NBLK, 256, 0, stream>>>(cnt, rowStart, bsum);
    k_scan2<<<1, 512, 0, stream>>>(bsum);
    k_scan3<<<NBLK, 256, 0, stream>>>(rowStart, bsum, cursor, cnt, dinv);
    k_fill<<<(NEDGE+255)/256, 256, 0, stream>>>(edges, cursor, csrSrc);

    // layer 1
    k_h1<<<(NNODES*HID)/256, 256, 0, stream>>>(graph_x, W1, dinv, bufA);
    k_agg<<<NNODES/8, 256, 0, stream>>>(rowStart, csrSrc, bufA, dinv, b1, bufC);

    // layer 2
    k_h2<<<NNODES/128, 256, 0, stream>>>(bufC, W2, dinv, bufA);
    k_agg<<<NNODES/8, 256, 0, stream>>>(rowStart, csrSrc, bufA, dinv, b2, bufC);

    // head
    k_head<<<NB, 256, 0, stream>>>(bufC, avail, pos, actions, steps,
                                   Wp1, bp1, Wp2, bp2, out);
}

// Round 4
// 390.625 us; speedup vs baseline: 11.7567x; 1.1227x over previous
//
#include <hip/hip_runtime.h>

#define NB 8
#define NN 10000
#define NE 160000
#define NNODES (NB*NN)          // 80000
#define NEDGE (NB*NE)           // 1280000
#define FIN 5
#define HID 128
#define EMB 256
#define ALAST 10
#define PROJ_IN (HID*5 + ALAST + 1)  // 651
#define NBLK ((NNODES+255)/256)      // 313

// count in-degree; record each edge's rank within its dst segment
__global__ void k_hist(const int* __restrict__ edges, int* __restrict__ cnt,
                       int* __restrict__ rank) {
    int e = blockIdx.x*256 + threadIdx.x;
    if (e >= NEDGE) return;
    int b = e / NE, w = e - b*NE;
    int d = edges[(size_t)b*2*NE + NE + w] + b*NN;
    rank[e] = atomicAdd(&cnt[d], 1);
}

__global__ void k_scan1(const int* __restrict__ cnt, int* __restrict__ rowStart,
                        int* __restrict__ bsum) {
    __shared__ int sh[256];
    int tid = threadIdx.x;
    int i = blockIdx.x*256 + tid;
    int v = (i < NNODES) ? cnt[i] : 0;
    sh[tid] = v;
    __syncthreads();
    for (int off = 1; off < 256; off <<= 1) {
        int t = (tid >= off) ? sh[tid - off] : 0;
        __syncthreads();
        sh[tid] += t;
        __syncthreads();
    }
    if (i < NNODES) rowStart[i] = sh[tid] - v;          // exclusive
    if (tid == 255) bsum[blockIdx.x] = sh[255];
}

__global__ void k_scan2(int* bsum) {
    __shared__ int sh[512];
    int tid = threadIdx.x;
    int v = (tid < NBLK) ? bsum[tid] : 0;
    sh[tid] = v;
    __syncthreads();
    for (int off = 1; off < 512; off <<= 1) {
        int t = (tid >= off) ? sh[tid - off] : 0;
        __syncthreads();
        sh[tid] += t;
        __syncthreads();
    }
    if (tid < NBLK) bsum[tid] = sh[tid] - v;            // exclusive
}

// add block offsets; compute dinv; prescale 5-dim features into SoA xs5
__global__ void k_scan3(int* __restrict__ rowStart, const int* __restrict__ bsum,
                        const int* __restrict__ cnt, float* __restrict__ dinv,
                        const float* __restrict__ x, float* __restrict__ xs5) {
    int i = blockIdx.x*256 + threadIdx.x;
    if (i < NNODES) {
        rowStart[i] = rowStart[i] + bsum[blockIdx.x];
        float dv = rsqrtf(1.0f + (float)cnt[i]);        // +1 = self loop
        dinv[i] = dv;
        #pragma unroll
        for (int f = 0; f < FIN; ++f)
            xs5[f*NNODES + i] = x[(size_t)i*FIN + f] * dv;
    }
    if (i == 0) rowStart[NNODES] = NEDGE;
}

// no atomics: position = rowStart[d] + rank[e]
__global__ void k_fill(const int* __restrict__ edges, const int* __restrict__ rowStart,
                       const int* __restrict__ rank, int* __restrict__ csrSrc) {
    int e = blockIdx.x*256 + threadIdx.x;
    if (e >= NEDGE) return;
    int b = e / NE, w = e - b*NE;
    int s = edges[(size_t)b*2*NE + w]      + b*NN;
    int d = edges[(size_t)b*2*NE + NE + w] + b*NN;
    csrSrc[rowStart[d] + rank[e]] = s;
}

// layer-1 aggregation on the 5 raw features (agg commutes with dense transform).
// thread per node; per-graph SoA slabs are 200KB -> L1/L2 resident.
__global__ __launch_bounds__(256) void k_agg5(
        const int* __restrict__ rowStart, const int* __restrict__ csrSrc,
        const float* __restrict__ xs5, const float* __restrict__ dinv,
        float* __restrict__ ax) {
    int g = blockIdx.x;
    int graph = g & 7;
    int nl = (g >> 3)*256 + threadIdx.x;
    if (nl >= NN) return;
    int n = graph*NN + nl;
    float a0 = xs5[0*NNODES + n], a1 = xs5[1*NNODES + n], a2 = xs5[2*NNODES + n],
          a3 = xs5[3*NNODES + n], a4 = xs5[4*NNODES + n];
    int beg = rowStart[n], end = rowStart[n+1];
    for (int e = beg; e < end; ++e) {
        int s = csrSrc[e];
        a0 += xs5[0*NNODES + s];
        a1 += xs5[1*NNODES + s];
        a2 += xs5[2*NNODES + s];
        a3 += xs5[3*NNODES + s];
        a4 += xs5[4*NNODES + s];
    }
    float dv = dinv[n];
    ax[(size_t)n*FIN + 0] = a0*dv;
    ax[(size_t)n*FIN + 1] = a1*dv;
    ax[(size_t)n*FIN + 2] = a2*dv;
    ax[(size_t)n*FIN + 3] = a3*dv;
    ax[(size_t)n*FIN + 4] = a4*dv;
}

// layer-1 dense on aggregated features: out = relu(ax @ W1^T + b1)
__global__ void k_h1(const float* __restrict__ ax, const float* __restrict__ W1,
                     const float* __restrict__ b1, float* __restrict__ out) {
    __shared__ float w[HID*FIN];
    __shared__ float bb[HID];
    for (int i = threadIdx.x; i < HID*FIN; i += 256) w[i] = W1[i];
    if (threadIdx.x < HID) bb[threadIdx.x] = b1[threadIdx.x];
    __syncthreads();
    int idx = blockIdx.x*256 + threadIdx.x;
    if (idx >= NNODES*HID) return;
    int n = idx >> 7;
    int j = idx & 127;
    const float* xr = ax + (size_t)n*FIN;
    const float* wr = w + j*FIN;
    float h = xr[0]*wr[0] + xr[1]*wr[1] + xr[2]*wr[2] + xr[3]*wr[3] + xr[4]*wr[4];
    out[idx] = fmaxf(h + bb[j], 0.0f);
}

// layer-2 gather agg over a 64-feature half; per-graph half-slab 2.56MB fits XCD L2
__global__ __launch_bounds__(256) void k_agg2(
        const int* __restrict__ rowStart, const int* __restrict__ csrSrc,
        const float* __restrict__ hs, const float* __restrict__ dinv,
        const float* __restrict__ bias, float* __restrict__ out, int half) {
    int g = blockIdx.x;
    int graph = g & 7;
    int i = g >> 3;                         // 0..1249
    int n = graph*NN + i*8 + (threadIdx.x >> 5);
    int lane = threadIdx.x & 31;
    int col = half*32 + lane;               // float2 column
    const float2* hp = (const float2*)hs;
    float2 acc = hp[(size_t)n*64 + col];    // self-loop message
    int beg = rowStart[n], end = rowStart[n+1];
    for (int e = beg; e < end; e += 32) {
        int m = end - e; if (m > 32) m = 32;
        int s = (lane < m) ? csrSrc[e + lane] : 0;
        for (int j = 0; j < m; ++j) {
            int sj = __shfl(s, j, 32);
            float2 v = hp[(size_t)sj*64 + col];
            acc.x += v.x; acc.y += v.y;
        }
    }
    float dv = dinv[n];
    float2 bb = ((const float2*)bias)[col];
    float2 o;
    o.x = fmaxf(acc.x*dv + bb.x, 0.0f);
    o.y = fmaxf(acc.y*dv + bb.y, 0.0f);
    ((float2*)out)[(size_t)n*64 + col] = o;
}

// Layer-2 dense: hs = (X @ W2^T) * dinv. 128x128 block tile, 8x8 per thread.
#define KC 32
__global__ __launch_bounds__(256) void k_h2(
        const float* __restrict__ x, const float* __restrict__ W2,
        const float* __restrict__ dinv, float* __restrict__ hs) {
    __shared__ float xs[KC*128];
    __shared__ float wt[KC*128];
    int tid = threadIdx.x;
    int m0g = blockIdx.x * 128;
    int tx = tid & 15, ty = tid >> 4;
    int m0 = ty*8;
    int j0 = tx*4;
    int r  = tid >> 1;                  // staging row 0..127
    int kq = (tid & 1) * 16;            // staging k sub-chunk
    float a[8][8];
    #pragma unroll
    for (int i = 0; i < 8; ++i)
        #pragma unroll
        for (int j = 0; j < 8; ++j) a[i][j] = 0.f;

    for (int kh = 0; kh < 128; kh += KC) {
        float4 xv[4], wv[4];
        #pragma unroll
        for (int c = 0; c < 4; ++c) {
            xv[c] = *(const float4*)&x[(size_t)(m0g + r)*128 + kh + kq + 4*c];
            wv[c] = *(const float4*)&W2[(size_t)r*128 + kh + kq + 4*c];
        }
        __syncthreads();               // protect prev iter's reads
        #pragma unroll
        for (int c = 0; c < 4; ++c) {
            xs[(kq+4*c+0)*128 + r] = xv[c].x;
            xs[(kq+4*c+1)*128 + r] = xv[c].y;
            xs[(kq+4*c+2)*128 + r] = xv[c].z;
            xs[(kq+4*c+3)*128 + r] = xv[c].w;
            wt[(kq+4*c+0)*128 + r] = wv[c].x;
            wt[(kq+4*c+1)*128 + r] = wv[c].y;
            wt[(kq+4*c+2)*128 + r] = wv[c].z;
            wt[(kq+4*c+3)*128 + r] = wv[c].w;
        }
        __syncthreads();
        for (int k = 0; k < KC; ++k) {
            float4 xa = *(const float4*)&xs[k*128 + m0];
            float4 xb = *(const float4*)&xs[k*128 + m0 + 4];
            float4 wa = *(const float4*)&wt[k*128 + j0];
            float4 wb = *(const float4*)&wt[k*128 + j0 + 64];
            float xr[8] = {xa.x,xa.y,xa.z,xa.w,xb.x,xb.y,xb.z,xb.w};
            float wr[8] = {wa.x,wa.y,wa.z,wa.w,wb.x,wb.y,wb.z,wb.w};
            #pragma unroll
            for (int i = 0; i < 8; ++i)
                #pragma unroll
                for (int j = 0; j < 8; ++j)
                    a[i][j] += xr[i]*wr[j];
        }
    }
    #pragma unroll
    for (int i = 0; i < 8; ++i) {
        int n = m0g + m0 + i;
        float dv = dinv[n];
        float4 v0 = make_float4(a[i][0]*dv, a[i][1]*dv, a[i][2]*dv, a[i][3]*dv);
        float4 v1 = make_float4(a[i][4]*dv, a[i][5]*dv, a[i][6]*dv, a[i][7]*dv);
        *(float4*)&hs[(size_t)n*HID + j0]      = v0;
        *(float4*)&hs[(size_t)n*HID + 64 + j0] = v1;
    }
}

// fused gather + MLP1 + MLP2, one block per batch row
__global__ __launch_bounds__(256) void k_head(
        const float* __restrict__ x, const int* __restrict__ avail,
        const int* __restrict__ pos, const float* __restrict__ actions,
        const float* __restrict__ steps,
        const float* __restrict__ Wp1, const float* __restrict__ bp1,
        const float* __restrict__ Wp2, const float* __restrict__ bp2,
        float* __restrict__ out) {
    int b = blockIdx.x;
    int t = threadIdx.x;
    __shared__ float c[PROJ_IN];
    __shared__ float hm[EMB];
    __shared__ int p[5];
    if (t < 4) p[t] = avail[b*4 + t] + b*NN;
    if (t == 4) p[4] = pos[b] + b*NN;
    __syncthreads();
    for (int i = t; i < 5*HID; i += 256) {
        int pi = i >> 7, j = i & 127;
        c[i] = x[(size_t)p[pi]*HID + j];
    }
    if (t < ALAST) c[5*HID + t] = actions[b*ALAST + t];
    if (t == ALAST) c[5*HID + ALAST] = steps[b];
    __syncthreads();
    {
        const float* wr = Wp1 + (size_t)t*PROJ_IN;
        float s = bp1[t];
        for (int k = 0; k < PROJ_IN; ++k) s += c[k]*wr[k];
        hm[t] = fmaxf(s, 0.f);
    }
    __syncthreads();
    {
        const float* wr = Wp2 + (size_t)t*EMB;
        float s = bp2[t];
        for (int k = 0; k < EMB; ++k) s += hm[k]*wr[k];
        out[b*EMB + t] = s;
    }
}

extern "C" void kernel_launch(void* const* d_in, const int* in_sizes, int n_in,
                              void* d_out, int out_size, void* d_ws, size_t ws_size,
                              hipStream_t stream) {
    const float* graph_x = (const float*)d_in[0];
    const int*   edges   = (const int*)d_in[1];
    const int*   pos     = (const int*)d_in[2];
    const int*   avail   = (const int*)d_in[3];
    const float* actions = (const float*)d_in[4];
    const float* steps   = (const float*)d_in[5];
    const float* W1  = (const float*)d_in[6];
    const float* b1  = (const float*)d_in[7];
    const float* W2  = (const float*)d_in[8];
    const float* b2  = (const float*)d_in[9];
    const float* Wp1 = (const float*)d_in[10];
    const float* bp1 = (const float*)d_in[11];
    const float* Wp2 = (const float*)d_in[12];
    const float* bp2 = (const float*)d_in[13];
    float* out = (float*)d_out;

    char* ws = (char*)d_ws;
    size_t off = 0;
    #define ALLOC(ptrname, type, nelem) \
        type* ptrname = (type*)(ws + off); off = (off + (size_t)(nelem)*sizeof(type) + 255) & ~(size_t)255;
    ALLOC(cnt,      int,   NNODES)
    ALLOC(rowStart, int,   NNODES+1)
    ALLOC(bsum,     int,   512)
    ALLOC(rank,     int,   NEDGE)
    ALLOC(csrSrc,   int,   NEDGE)
    ALLOC(dinv,     float, NNODES)
    ALLOC(xs5,      float, (size_t)NNODES*FIN)   // SoA prescaled input
    ALLOC(ax,       float, (size_t)NNODES*FIN)   // aggregated 5-dim
    ALLOC(bufA,     float, (size_t)NNODES*HID)   // hs (layer-2 staging)
    ALLOC(bufC,     float, (size_t)NNODES*HID)   // layer outputs
    #undef ALLOC

    hipMemsetAsync(cnt, 0, (size_t)NNODES*4, stream);
    k_hist<<<(NEDGE+255)/256, 256, 0, stream>>>(edges, cnt, rank);
    k_scan1<<<NBLK, 256, 0, stream>>>(cnt, rowStart, bsum);
    k_scan2<<<1, 512, 0, stream>>>(bsum);
    k_scan3<<<NBLK, 256, 0, stream>>>(rowStart, bsum, cnt, dinv, graph_x, xs5);
    k_fill<<<(NEDGE+255)/256, 256, 0, stream>>>(edges, rowStart, rank, csrSrc);

    // layer 1: aggregate 5-dim, then dense+bias+relu
    k_agg5<<<8*((NN+255)/256), 256, 0, stream>>>(rowStart, csrSrc, xs5, dinv, ax);
    k_h1<<<(NNODES*HID)/256, 256, 0, stream>>>(ax, W1, b1, bufC);

    // layer 2: dense, then aggregate per 64-feature half
    k_h2<<<NNODES/128, 256, 0, stream>>>(bufC, W2, dinv, bufA);
    k_agg2<<<NNODES/8, 256, 0, stream>>>(rowStart, csrSrc, bufA, dinv, b2, bufC, 0);
    k_agg2<<<NNODES/8, 256, 0, stream>>>(rowStart, csrSrc, bufA, dinv, b2, bufC, 1);

    // head
    k_head<<<NB, 256, 0, stream>>>(bufC, avail, pos, actions, steps,
                                   Wp1, bp1, Wp2, bp2, out);
}

// Round 5
// 364.508 us; speedup vs baseline: 12.5991x; 1.0716x over previous
//
#include <hip/hip_runtime.h>

#define NB 8
#define NN 10000
#define NE 160000
#define NNODES (NB*NN)          // 80000
#define NEDGE (NB*NE)           // 1280000
#define FIN 5
#define HID 128
#define EMB 256
#define ALAST 10
#define PROJ_IN (HID*5 + ALAST + 1)  // 651
#define NBLK ((NNODES+255)/256)      // 313

// count in-degree; record each edge's rank within its dst segment
__global__ void k_hist(const int* __restrict__ edges, int* __restrict__ cnt,
                       int* __restrict__ rank) {
    int e = blockIdx.x*256 + threadIdx.x;
    if (e >= NEDGE) return;
    int b = e / NE, w = e - b*NE;
    int d = edges[(size_t)b*2*NE + NE + w] + b*NN;
    rank[e] = atomicAdd(&cnt[d], 1);
}

__global__ void k_scan1(const int* __restrict__ cnt, int* __restrict__ rowStart,
                        int* __restrict__ bsum) {
    __shared__ int sh[256];
    int tid = threadIdx.x;
    int i = blockIdx.x*256 + tid;
    int v = (i < NNODES) ? cnt[i] : 0;
    sh[tid] = v;
    __syncthreads();
    for (int off = 1; off < 256; off <<= 1) {
        int t = (tid >= off) ? sh[tid - off] : 0;
        __syncthreads();
        sh[tid] += t;
        __syncthreads();
    }
    if (i < NNODES) rowStart[i] = sh[tid] - v;          // exclusive
    if (tid == 255) bsum[blockIdx.x] = sh[255];
}

__global__ void k_scan2(int* bsum) {
    __shared__ int sh[512];
    int tid = threadIdx.x;
    int v = (tid < NBLK) ? bsum[tid] : 0;
    sh[tid] = v;
    __syncthreads();
    for (int off = 1; off < 512; off <<= 1) {
        int t = (tid >= off) ? sh[tid - off] : 0;
        __syncthreads();
        sh[tid] += t;
        __syncthreads();
    }
    if (tid < NBLK) bsum[tid] = sh[tid] - v;            // exclusive
}

// add block offsets; compute dinv; prescale 5-dim features into SoA xs5
__global__ void k_scan3(int* __restrict__ rowStart, const int* __restrict__ bsum,
                        const int* __restrict__ cnt, float* __restrict__ dinv,
                        const float* __restrict__ x, float* __restrict__ xs5) {
    int i = blockIdx.x*256 + threadIdx.x;
    if (i < NNODES) {
        rowStart[i] = rowStart[i] + bsum[blockIdx.x];
        float dv = rsqrtf(1.0f + (float)cnt[i]);        // +1 = self loop
        dinv[i] = dv;
        #pragma unroll
        for (int f = 0; f < FIN; ++f)
            xs5[f*NNODES + i] = x[(size_t)i*FIN + f] * dv;
    }
    if (i == 0) rowStart[NNODES] = NEDGE;
}

// no atomics: position = rowStart[d] + rank[e]
__global__ void k_fill(const int* __restrict__ edges, const int* __restrict__ rowStart,
                       const int* __restrict__ rank, int* __restrict__ csrSrc) {
    int e = blockIdx.x*256 + threadIdx.x;
    if (e >= NEDGE) return;
    int b = e / NE, w = e - b*NE;
    int s = edges[(size_t)b*2*NE + w]      + b*NN;
    int d = edges[(size_t)b*2*NE + NE + w] + b*NN;
    csrSrc[rowStart[d] + rank[e]] = s;
}

// layer-1 aggregation on the 5 raw features (agg commutes with dense transform).
__global__ __launch_bounds__(256) void k_agg5(
        const int* __restrict__ rowStart, const int* __restrict__ csrSrc,
        const float* __restrict__ xs5, const float* __restrict__ dinv,
        float* __restrict__ ax) {
    int g = blockIdx.x;
    int graph = g & 7;
    int nl = (g >> 3)*256 + threadIdx.x;
    if (nl >= NN) return;
    int n = graph*NN + nl;
    float a0 = xs5[0*NNODES + n], a1 = xs5[1*NNODES + n], a2 = xs5[2*NNODES + n],
          a3 = xs5[3*NNODES + n], a4 = xs5[4*NNODES + n];
    int beg = rowStart[n], end = rowStart[n+1];
    for (int e = beg; e < end; ++e) {
        int s = csrSrc[e];
        a0 += xs5[0*NNODES + s];
        a1 += xs5[1*NNODES + s];
        a2 += xs5[2*NNODES + s];
        a3 += xs5[3*NNODES + s];
        a4 += xs5[4*NNODES + s];
    }
    float dv = dinv[n];
    ax[(size_t)n*FIN + 0] = a0*dv;
    ax[(size_t)n*FIN + 1] = a1*dv;
    ax[(size_t)n*FIN + 2] = a2*dv;
    ax[(size_t)n*FIN + 3] = a3*dv;
    ax[(size_t)n*FIN + 4] = a4*dv;
}

// layer-1 dense on aggregated features: out = relu(ax @ W1^T + b1)
__global__ void k_h1(const float* __restrict__ ax, const float* __restrict__ W1,
                     const float* __restrict__ b1, float* __restrict__ out) {
    __shared__ float w[HID*FIN];
    __shared__ float bb[HID];
    for (int i = threadIdx.x; i < HID*FIN; i += 256) w[i] = W1[i];
    if (threadIdx.x < HID) bb[threadIdx.x] = b1[threadIdx.x];
    __syncthreads();
    int idx = blockIdx.x*256 + threadIdx.x;
    if (idx >= NNODES*HID) return;
    int n = idx >> 7;
    int j = idx & 127;
    const float* xr = ax + (size_t)n*FIN;
    const float* wr = w + j*FIN;
    float h = xr[0]*wr[0] + xr[1]*wr[1] + xr[2]*wr[2] + xr[3]*wr[3] + xr[4]*wr[4];
    out[idx] = fmaxf(h + bb[j], 0.0f);
}

// layer-2 gather agg over a 64-feature half; per-graph half-slab 2.56MB fits XCD L2
__global__ __launch_bounds__(256) void k_agg2(
        const int* __restrict__ rowStart, const int* __restrict__ csrSrc,
        const float* __restrict__ hs, const float* __restrict__ dinv,
        const float* __restrict__ bias, float* __restrict__ out, int half) {
    int g = blockIdx.x;
    int graph = g & 7;
    int i = g >> 3;                         // 0..1249
    int n = graph*NN + i*8 + (threadIdx.x >> 5);
    int lane = threadIdx.x & 31;
    int col = half*32 + lane;               // float2 column
    const float2* hp = (const float2*)hs;
    float2 acc = hp[(size_t)n*64 + col];    // self-loop message
    int beg = rowStart[n], end = rowStart[n+1];
    for (int e = beg; e < end; e += 32) {
        int m = end - e; if (m > 32) m = 32;
        int s = (lane < m) ? csrSrc[e + lane] : 0;
        for (int j = 0; j < m; ++j) {
            int sj = __shfl(s, j, 32);
            float2 v = hp[(size_t)sj*64 + col];
            acc.x += v.x; acc.y += v.y;
        }
    }
    float dv = dinv[n];
    float2 bb = ((const float2*)bias)[col];
    float2 o;
    o.x = fmaxf(acc.x*dv + bb.x, 0.0f);
    o.y = fmaxf(acc.y*dv + bb.y, 0.0f);
    ((float2*)out)[(size_t)n*64 + col] = o;
}

// Layer-2 dense: hs = (X @ W2^T) * dinv. 128x128 block tile, 8x8 per thread.
#define KC 32
__global__ __launch_bounds__(256) void k_h2(
        const float* __restrict__ x, const float* __restrict__ W2,
        const float* __restrict__ dinv, float* __restrict__ hs) {
    __shared__ float xs[KC*128];
    __shared__ float wt[KC*128];
    int tid = threadIdx.x;
    int m0g = blockIdx.x * 128;
    int tx = tid & 15, ty = tid >> 4;
    int m0 = ty*8;
    int j0 = tx*4;
    int r  = tid >> 1;                  // staging row 0..127
    int kq = (tid & 1) * 16;            // staging k sub-chunk
    float a[8][8];
    #pragma unroll
    for (int i = 0; i < 8; ++i)
        #pragma unroll
        for (int j = 0; j < 8; ++j) a[i][j] = 0.f;

    for (int kh = 0; kh < 128; kh += KC) {
        float4 xv[4], wv[4];
        #pragma unroll
        for (int c = 0; c < 4; ++c) {
            xv[c] = *(const float4*)&x[(size_t)(m0g + r)*128 + kh + kq + 4*c];
            wv[c] = *(const float4*)&W2[(size_t)r*128 + kh + kq + 4*c];
        }
        __syncthreads();               // protect prev iter's reads
        #pragma unroll
        for (int c = 0; c < 4; ++c) {
            xs[(kq+4*c+0)*128 + r] = xv[c].x;
            xs[(kq+4*c+1)*128 + r] = xv[c].y;
            xs[(kq+4*c+2)*128 + r] = xv[c].z;
            xs[(kq+4*c+3)*128 + r] = xv[c].w;
            wt[(kq+4*c+0)*128 + r] = wv[c].x;
            wt[(kq+4*c+1)*128 + r] = wv[c].y;
            wt[(kq+4*c+2)*128 + r] = wv[c].z;
            wt[(kq+4*c+3)*128 + r] = wv[c].w;
        }
        __syncthreads();
        for (int k = 0; k < KC; ++k) {
            float4 xa = *(const float4*)&xs[k*128 + m0];
            float4 xb = *(const float4*)&xs[k*128 + m0 + 4];
            float4 wa = *(const float4*)&wt[k*128 + j0];
            float4 wb = *(const float4*)&wt[k*128 + j0 + 64];
            float xr[8] = {xa.x,xa.y,xa.z,xa.w,xb.x,xb.y,xb.z,xb.w};
            float wr[8] = {wa.x,wa.y,wa.z,wa.w,wb.x,wb.y,wb.z,wb.w};
            #pragma unroll
            for (int i = 0; i < 8; ++i)
                #pragma unroll
                for (int j = 0; j < 8; ++j)
                    a[i][j] += xr[i]*wr[j];
        }
    }
    #pragma unroll
    for (int i = 0; i < 8; ++i) {
        int n = m0g + m0 + i;
        float dv = dinv[n];
        float4 v0 = make_float4(a[i][0]*dv, a[i][1]*dv, a[i][2]*dv, a[i][3]*dv);
        float4 v1 = make_float4(a[i][4]*dv, a[i][5]*dv, a[i][6]*dv, a[i][7]*dv);
        *(float4*)&hs[(size_t)n*HID + j0]      = v0;
        *(float4*)&hs[(size_t)n*HID + 64 + j0] = v1;
    }
}

// MLP1: block per (batch, 16-output group); 16 lanes per output, shuffle-reduce.
__global__ __launch_bounds__(256) void k_mlp1(
        const float* __restrict__ x, const int* __restrict__ avail,
        const int* __restrict__ pos, const float* __restrict__ actions,
        const float* __restrict__ steps,
        const float* __restrict__ Wp1, const float* __restrict__ bp1,
        float* __restrict__ hm) {
    int b  = blockIdx.x >> 4;
    int jg = blockIdx.x & 15;
    int t  = threadIdx.x;
    __shared__ float c[PROJ_IN];
    __shared__ int p[5];
    if (t < 4) p[t] = avail[b*4 + t] + b*NN;
    if (t == 4) p[4] = pos[b] + b*NN;
    __syncthreads();
    for (int i = t; i < 5*HID; i += 256)
        c[i] = x[(size_t)p[i >> 7]*HID + (i & 127)];
    if (t < ALAST) c[5*HID + t] = actions[b*ALAST + t];
    if (t == ALAST) c[5*HID + ALAST] = steps[b];
    __syncthreads();
    int o = t >> 4, sub = t & 15;
    int j = jg*16 + o;
    const float* wr = Wp1 + (size_t)j*PROJ_IN;
    float s = 0.f;
    for (int k = sub; k < PROJ_IN; k += 16) s += c[k]*wr[k];
    #pragma unroll
    for (int d = 8; d; d >>= 1) s += __shfl_down(s, d, 16);
    if (sub == 0) hm[b*EMB + j] = fmaxf(s + bp1[j], 0.f);
}

// MLP2: block per (batch, 16-output group); 16 lanes per output, shuffle-reduce.
__global__ __launch_bounds__(256) void k_mlp2(
        const float* __restrict__ hm, const float* __restrict__ Wp2,
        const float* __restrict__ bp2, float* __restrict__ out) {
    int b  = blockIdx.x >> 4;
    int jg = blockIdx.x & 15;
    int t  = threadIdx.x;
    __shared__ float c[EMB];
    if (t < EMB) c[t] = hm[b*EMB + t];
    __syncthreads();
    int o = t >> 4, sub = t & 15;
    int j = jg*16 + o;
    const float* wr = Wp2 + (size_t)j*EMB;
    float s = 0.f;
    for (int k = sub; k < EMB; k += 16) s += c[k]*wr[k];
    #pragma unroll
    for (int d = 8; d; d >>= 1) s += __shfl_down(s, d, 16);
    if (sub == 0) out[b*EMB + j] = s + bp2[j];
}

extern "C" void kernel_launch(void* const* d_in, const int* in_sizes, int n_in,
                              void* d_out, int out_size, void* d_ws, size_t ws_size,
                              hipStream_t stream) {
    const float* graph_x = (const float*)d_in[0];
    const int*   edges   = (const int*)d_in[1];
    const int*   pos     = (const int*)d_in[2];
    const int*   avail   = (const int*)d_in[3];
    const float* actions = (const float*)d_in[4];
    const float* steps   = (const float*)d_in[5];
    const float* W1  = (const float*)d_in[6];
    const float* b1  = (const float*)d_in[7];
    const float* W2  = (const float*)d_in[8];
    const float* b2  = (const float*)d_in[9];
    const float* Wp1 = (const float*)d_in[10];
    const float* bp1 = (const float*)d_in[11];
    const float* Wp2 = (const float*)d_in[12];
    const float* bp2 = (const float*)d_in[13];
    float* out = (float*)d_out;

    char* ws = (char*)d_ws;
    size_t off = 0;
    #define ALLOC(ptrname, type, nelem) \
        type* ptrname = (type*)(ws + off); off = (off + (size_t)(nelem)*sizeof(type) + 255) & ~(size_t)255;
    ALLOC(cnt,      int,   NNODES)
    ALLOC(rowStart, int,   NNODES+1)
    ALLOC(bsum,     int,   512)
    ALLOC(rank,     int,   NEDGE)
    ALLOC(csrSrc,   int,   NEDGE)
    ALLOC(dinv,     float, NNODES)
    ALLOC(xs5,      float, (size_t)NNODES*FIN)   // SoA prescaled input
    ALLOC(ax,       float, (size_t)NNODES*FIN)   // aggregated 5-dim
    ALLOC(bufA,     float, (size_t)NNODES*HID)   // hs (layer-2 staging)
    ALLOC(bufC,     float, (size_t)NNODES*HID)   // layer outputs
    ALLOC(hm,       float, (size_t)NB*EMB)
    #undef ALLOC

    hipMemsetAsync(cnt, 0, (size_t)NNODES*4, stream);
    k_hist<<<(NEDGE+255)/256, 256, 0, stream>>>(edges, cnt, rank);
    k_scan1<<<NBLK, 256, 0, stream>>>(cnt, rowStart, bsum);
    k_scan2<<<1, 512, 0, stream>>>(bsum);
    k_scan3<<<NBLK, 256, 0, stream>>>(rowStart, bsum, cnt, dinv, graph_x, xs5);
    k_fill<<<(NEDGE+255)/256, 256, 0, stream>>>(edges, rowStart, rank, csrSrc);

    // layer 1: aggregate 5-dim, then dense+bias+relu
    k_agg5<<<8*((NN+255)/256), 256, 0, stream>>>(rowStart, csrSrc, xs5, dinv, ax);
    k_h1<<<(NNODES*HID)/256, 256, 0, stream>>>(ax, W1, b1, bufC);

    // layer 2: dense, then aggregate per 64-feature half
    k_h2<<<NNODES/128, 256, 0, stream>>>(bufC, W2, dinv, bufA);
    k_agg2<<<NNODES/8, 256, 0, stream>>>(rowStart, csrSrc, bufA, dinv, b2, bufC, 0);
    k_agg2<<<NNODES/8, 256, 0, stream>>>(rowStart, csrSrc, bufA, dinv, b2, bufC, 1);

    // head: parallel MLPs (the single-block-per-batch version was latency-bound)
    k_mlp1<<<NB*16, 256, 0, stream>>>(bufC, avail, pos, actions, steps, Wp1, bp1, hm);
    k_mlp2<<<NB*16, 256, 0, stream>>>(hm, Wp2, bp2, out);
}